// Round 1
// 1393.050 us; speedup vs baseline: 1.0699x; 1.0699x over previous
//
#include <hip/hip_runtime.h>
#include <cstdint>
#include <math.h>

typedef unsigned short u16;
typedef __bf16 bf16x8 __attribute__((ext_vector_type(8)));
typedef float f32x4 __attribute__((ext_vector_type(4)));
typedef unsigned int u32x4 __attribute__((ext_vector_type(4)));

#define NH 24
#define DHEAD 128
#define SEQ 2560
#define SEQB 512
#define DMODEL 3072
#define NQKV 9216
// fold attn scale and log2(e) into Q so softmax can use exp2 (v_exp_f32)
#define QSCALE (0.08838834764831845f * 1.4426950408889634f)

__device__ __forceinline__ float bf2f(u16 b) {
  unsigned u = ((unsigned)b) << 16;
  return __builtin_bit_cast(float, u);
}
__device__ __forceinline__ u16 f2bf(float f) {
  unsigned u = __builtin_bit_cast(unsigned, f);
  u += 0x7fffu + ((u >> 16) & 1u);
  return (u16)(u >> 16);
}
__device__ __forceinline__ unsigned pack2(float a, float b) {
  return (unsigned)f2bf(a) | ((unsigned)f2bf(b) << 16);
}

// ---------------- dtype detector: fp32 buffers read as u16 contain mantissa
// fragments whose bf16-exponent field is 0xFF with p~1/256; bf16 N(0,1) data never does.
__global__ __launch_bounds__(256) void detect_dtype(const u16* __restrict__ x, int* __restrict__ flag) {
  __shared__ int cnt;
  if (threadIdx.x == 0) cnt = 0;
  __syncthreads();
  int local = 0;
  for (int i = threadIdx.x; i < 262144; i += 256) {
    if ((x[i] & 0x7F80u) == 0x7F80u) local++;
  }
  atomicAdd(&cnt, local);
  __syncthreads();
  if (threadIdx.x == 0) *flag = (cnt > 0) ? 1 : 0;
}

// ---------------- ingest: convert fp32 -> bf16 (flag=1) or copy bf16 (flag=0)
__global__ __launch_bounds__(256) void ingest(const void* __restrict__ src, u16* __restrict__ dst,
                                              int n, const int* __restrict__ flag) {
  const bool f32 = (*flag) != 0;
  int idx = (blockIdx.x * 256 + threadIdx.x) * 8;
  if (idx + 8 <= n) {
    if (f32) {
      const float* s = (const float*)src;
      float4 v0 = *(const float4*)(s + idx);
      float4 v1 = *(const float4*)(s + idx + 4);
      u16 t[8] = {f2bf(v0.x), f2bf(v0.y), f2bf(v0.z), f2bf(v0.w),
                  f2bf(v1.x), f2bf(v1.y), f2bf(v1.z), f2bf(v1.w)};
      *(u32x4*)(dst + idx) = *(u32x4*)t;
    } else {
      *(u32x4*)(dst + idx) = *(const u32x4*)((const u16*)src + idx);
    }
  } else if (idx < n) {
    for (int j = idx; j < n; ++j)
      dst[j] = f32 ? f2bf(((const float*)src)[j]) : ((const u16*)src)[j];
  }
}

// ---------------- GEMM: out[M][N] = X[M][K] * W[N][K]^T + bias, bf16 in ws, fp32 acc
// 128x128 tile, BK=32, 4 waves x 4x4 MFMA subtiles. bias is EXTERNAL (dtype per flag).
// Output: ws bf16 segments (ext_out=0) or d_out (ext_out=1, dtype per flag), with orow0 row offset.
__global__ __launch_bounds__(256) void gemm_bt(
    const u16* __restrict__ X, const u16* __restrict__ Wt, const void* __restrict__ bias,
    void* __restrict__ out0, void* __restrict__ out1, void* __restrict__ out2,
    int M, int N, int K, const int* __restrict__ flag, int ext_out, int orow0) {
  __shared__ __align__(16) u16 Asub[128 * 32];
  __shared__ __align__(16) u16 Bsub[128 * 32];
  const int tid = threadIdx.x;
  const int wv = tid >> 6, lane = tid & 63;
  const int lhi = lane >> 4, llo = lane & 15;
  const int n0 = blockIdx.x * 128, m0 = blockIdx.y * 128;
  const int wrow = wv >> 1, wcol = wv & 1;
  f32x4 acc[4][4] = {};
  for (int k0 = 0; k0 < K; k0 += 32) {
    u32x4 areg[2], breg[2];
#pragma unroll
    for (int is = 0; is < 2; ++is) {
      int chunk = is * 256 + tid;  // 0..511
      int row = chunk >> 2, kc = (chunk & 3) << 3;
      areg[is] = *(const u32x4*)(X + (size_t)(m0 + row) * K + k0 + kc);
      breg[is] = *(const u32x4*)(Wt + (size_t)(n0 + row) * K + k0 + kc);
    }
    __syncthreads();
#pragma unroll
    for (int is = 0; is < 2; ++is) {
      int chunk = is * 256 + tid;
      *(u32x4*)&Asub[chunk * 8] = areg[is];
      *(u32x4*)&Bsub[chunk * 8] = breg[is];
    }
    __syncthreads();
    bf16x8 af[4], bfr[4];
#pragma unroll
    for (int t = 0; t < 4; ++t) {
      af[t] = *(const bf16x8*)&Asub[(wrow * 64 + t * 16 + llo) * 32 + lhi * 8];
      bfr[t] = *(const bf16x8*)&Bsub[(wcol * 64 + t * 16 + llo) * 32 + lhi * 8];
    }
#pragma unroll
    for (int i = 0; i < 4; ++i)
#pragma unroll
      for (int j = 0; j < 4; ++j)
        acc[i][j] = __builtin_amdgcn_mfma_f32_16x16x32_bf16(af[i], bfr[j], acc[i][j], 0, 0, 0);
  }
  const bool f32 = (*flag) != 0;
  const int seg = n0 / DMODEL;
  void* ob = seg == 0 ? out0 : (seg == 1 ? out1 : out2);
  const int ocol0 = n0 - seg * DMODEL;
  // epilogue: C/D layout row=(lane>>4)*4+r, col=lane&15
#pragma unroll
  for (int i = 0; i < 4; ++i) {
    int row = m0 + wrow * 64 + i * 16 + lhi * 4;
#pragma unroll
    for (int j = 0; j < 4; ++j) {
      int colin = wcol * 64 + j * 16 + llo;
      float b = f32 ? ((const float*)bias)[n0 + colin] : bf2f(((const u16*)bias)[n0 + colin]);
#pragma unroll
      for (int r = 0; r < 4; ++r) {
        float v = acc[i][j][r] + b;
        size_t off = (size_t)(orow0 + row + r) * DMODEL + ocol0 + colin;
        if (ext_out && f32) ((float*)ob)[off] = v;
        else ((u16*)ob)[off] = f2bf(v);
      }
    }
  }
}

// ---------------- RMS-norm + RoPE for Q,K, IN PLACE on Qraw/Kraw [s][3072] (bf16 ws)
// rope + norm weights are EXTERNAL (dtype per flag). 1 wave; lane holds d=2j,2j+1.
__global__ __launch_bounds__(64) void normrope(
    u16* __restrict__ Qraw, u16* __restrict__ Kraw, const void* __restrict__ rope,
    const void* __restrict__ nqa, const void* __restrict__ nka,
    const void* __restrict__ nqb, const void* __restrict__ nkb,
    const int* __restrict__ flag) {
  const bool f32 = (*flag) != 0;
  int bid = blockIdx.x;
  int which = bid & 1;  // 0=q 1=k
  int h = (bid >> 1) % NH;
  int s = bid / (NH * 2);
  int lane = threadIdx.x;
  u16* ptr = (which ? Kraw : Qraw) + (size_t)s * DMODEL + h * DHEAD + lane * 2;
  unsigned xv = *(const unsigned*)ptr;
  float x0 = bf2f((u16)(xv & 0xffff)), x1 = bf2f((u16)(xv >> 16));
  float ss = x0 * x0 + x1 * x1;
#pragma unroll
  for (int m = 1; m < 64; m <<= 1) ss += __shfl_xor(ss, m, 64);
  float rn = rsqrtf(ss * (1.0f / 128.0f) + 1e-6f);
  const void* wn = which ? (s < SEQB ? nkb : nka) : (s < SEQB ? nqb : nqa);
  float w0, w1;
  if (f32) {
    w0 = ((const float*)wn)[lane * 2];
    w1 = ((const float*)wn)[lane * 2 + 1];
  } else {
    unsigned wv2 = *(const unsigned*)((const u16*)wn + lane * 2);
    w0 = bf2f((u16)(wv2 & 0xffff));
    w1 = bf2f((u16)(wv2 >> 16));
  }
  float y0 = x0 * rn * w0;
  float y1 = x1 * rn * w1;
  // rope table: [s][64][2][2] = [[cos,-sin],[sin,cos]] -> elem0=cos, elem2=sin
  float c, sn;
  if (f32) {
    const float* rp = (const float*)rope + ((size_t)s * 64 + lane) * 4;
    float4 rv = *(const float4*)rp;
    c = rv.x;
    sn = rv.z;
  } else {
    const u16* rp = (const u16*)rope + ((size_t)s * 64 + lane) * 4;
    uint2 rv = *(const uint2*)rp;
    c = bf2f((u16)(rv.x & 0xffff));
    sn = bf2f((u16)(rv.y & 0xffff));
  }
  float o0 = c * y0 - sn * y1;
  float o1 = sn * y0 + c * y1;
  if (!which) { o0 *= QSCALE; o1 *= QSCALE; }
  *(unsigned*)ptr = pack2(o0, o1);
}

// ---------------- V transpose Vraw[s][3072] -> Vt (h, d=128, s=2560)  (bf16 ws only)
__global__ __launch_bounds__(256) void build_vt(const u16* __restrict__ Vraw, u16* __restrict__ Vt) {
  __shared__ u16 tile[64][66];
  int h = blockIdx.x, st = blockIdx.y, dt = blockIdx.z;
  int s0 = st * 64, d0 = dt * 64;
  int t = threadIdx.x;
  int sl = t >> 5, dp = (t & 31) << 1;
#pragma unroll
  for (int it = 0; it < 8; ++it) {
    int srow = sl + it * 8;
    unsigned v = *(const unsigned*)(Vraw + (size_t)(s0 + srow) * DMODEL + h * DHEAD + d0 + dp);
    tile[srow][dp] = (u16)(v & 0xffff);
    tile[srow][dp + 1] = (u16)(v >> 16);
  }
  __syncthreads();
  int dl = t >> 5, sp = (t & 31) << 1;
#pragma unroll
  for (int it = 0; it < 8; ++it) {
    int drow = dl + it * 8;
    unsigned v = (unsigned)tile[sp][drow] | ((unsigned)tile[sp + 1][drow] << 16);
    *(unsigned*)(Vt + ((size_t)h * DHEAD + d0 + drow) * SEQ + s0 + sp) = v;
  }
}

// ---------------- flash attention: 4 waves, 64 q-rows (16/wave), K-block 32 (bf16 ws only)
// LDS layouts padded for bank-conflict-free access:
//   Klds row stride 136 u16 (272 B = 68 dwords == 4 mod 32) -> reads & writes bank-even
//   Plds row stride 40 u16 (80 B = 20 dwords) -> read bank-even, write ~4-way (was 8)
//   Vtlds unpadded: stride 16 dwords already distributes start banks evenly
#define KSTRIDE 136
#define PSTRIDE 40
__global__ __launch_bounds__(256) void attn(
    const u16* __restrict__ Q, const u16* __restrict__ Kd, const u16* __restrict__ Vt,
    u16* __restrict__ O) {
  __shared__ __align__(16) u16 Klds[32 * KSTRIDE];     // [kk][d] padded
  __shared__ __align__(16) u16 Vtlds[128 * 32];        // [d][kk]
  __shared__ __align__(16) u16 Plds[4][16 * PSTRIDE];  // per-wave [qrow][kk] padded
  const int q0 = blockIdx.x * 64;
  const int h = blockIdx.y;
  const int tid = threadIdx.x, wv = tid >> 6, lane = tid & 63;
  const int lhi = lane >> 4, llo = lane & 15;
  bf16x8 qf[4];
  const u16* qbase = Q + (size_t)(q0 + wv * 16 + llo) * DMODEL + h * DHEAD + lhi * 8;
#pragma unroll
  for (int f = 0; f < 4; ++f) qf[f] = *(const bf16x8*)(qbase + f * 32);
  float m_[4], l_[4];
  f32x4 oacc[8] = {};
#pragma unroll
  for (int r = 0; r < 4; ++r) { m_[r] = -1e30f; l_[r] = 0.f; }
  for (int kb = 0; kb < SEQ; kb += 32) {
    u32x4 kvv[2], vvv[2];
#pragma unroll
    for (int is = 0; is < 2; ++is) {
      int chunk = is * 256 + tid;
      kvv[is] = *(const u32x4*)(Kd + (size_t)(kb + (chunk >> 4)) * DMODEL + h * DHEAD + ((chunk & 15) << 3));
      vvv[is] = *(const u32x4*)(Vt + ((size_t)h * DHEAD + (chunk >> 2)) * SEQ + kb + ((chunk & 3) << 3));
    }
    __syncthreads();
#pragma unroll
    for (int is = 0; is < 2; ++is) {
      int chunk = is * 256 + tid;
      int krow = chunk >> 4, kslot = chunk & 15;
      *(u32x4*)&Klds[krow * KSTRIDE + kslot * 8] = kvv[is];
      *(u32x4*)&Vtlds[chunk * 8] = vvv[is];
    }
    __syncthreads();
    f32x4 sc[2];
#pragma unroll
    for (int ct = 0; ct < 2; ++ct) {
      f32x4 a = {};
#pragma unroll
      for (int f = 0; f < 4; ++f) {
        bf16x8 kf = *(const bf16x8*)&Klds[(ct * 16 + llo) * KSTRIDE + f * 32 + lhi * 8];
        a = __builtin_amdgcn_mfma_f32_16x16x32_bf16(qf[f], kf, a, 0, 0, 0);
      }
      sc[ct] = a;
    }
    float mnew[4], alpha[4];
#pragma unroll
    for (int r = 0; r < 4; ++r) {
      float mx = fmaxf(sc[0][r], sc[1][r]);
#pragma unroll
      for (int t = 1; t < 16; t <<= 1) mx = fmaxf(mx, __shfl_xor(mx, t, 64));
      mnew[r] = fmaxf(m_[r], mx);
      alpha[r] = exp2f(m_[r] - mnew[r]);
      m_[r] = mnew[r];
    }
    float p[2][4];
#pragma unroll
    for (int ct = 0; ct < 2; ++ct)
#pragma unroll
      for (int r = 0; r < 4; ++r) p[ct][r] = exp2f(sc[ct][r] - mnew[r]);
#pragma unroll
    for (int r = 0; r < 4; ++r) {
      float s = p[0][r] + p[1][r];
#pragma unroll
      for (int t = 1; t < 16; t <<= 1) s += __shfl_xor(s, t, 64);
      l_[r] = l_[r] * alpha[r] + s;
    }
#pragma unroll
    for (int dt = 0; dt < 8; ++dt)
#pragma unroll
      for (int r = 0; r < 4; ++r) oacc[dt][r] *= alpha[r];
    u16* pw = &Plds[wv][0];
#pragma unroll
    for (int ct = 0; ct < 2; ++ct)
#pragma unroll
      for (int r = 0; r < 4; ++r) pw[(lhi * 4 + r) * PSTRIDE + ct * 16 + llo] = f2bf(p[ct][r]);
    // no __syncthreads needed: Plds is per-wave; compiler's lgkmcnt ordering covers the
    // write->read dependency, and Klds/Vtlds restaging is guarded by the loop-top barrier.
    bf16x8 pf = *(const bf16x8*)&Plds[wv][llo * PSTRIDE + lhi * 8];
#pragma unroll
    for (int dt = 0; dt < 8; ++dt) {
      bf16x8 vf = *(const bf16x8*)&Vtlds[(dt * 16 + llo) * 32 + lhi * 8];
      oacc[dt] = __builtin_amdgcn_mfma_f32_16x16x32_bf16(pf, vf, oacc[dt], 0, 0, 0);
    }
  }
  float inv[4];
#pragma unroll
  for (int r = 0; r < 4; ++r) inv[r] = 1.0f / l_[r];
#pragma unroll
  for (int dt = 0; dt < 8; ++dt)
#pragma unroll
    for (int r = 0; r < 4; ++r) {
      int row = q0 + wv * 16 + lhi * 4 + r;
      int col = h * DHEAD + dt * 16 + llo;
      O[(size_t)row * DMODEL + col] = f2bf(oacc[dt][r] * inv[r]);
    }
}

extern "C" void kernel_launch(void* const* d_in, const int* in_sizes, int n_in,
                              void* d_out, int out_size, void* d_ws, size_t ws_size,
                              hipStream_t stream) {
  const void* hsa = d_in[0];
  const void* hsb = d_in[1];
  const void* rope = d_in[2];
  const void* aqw = d_in[3];
  const void* aqb = d_in[4];
  const void* bqw = d_in[5];
  const void* bqb = d_in[6];
  const void* nqa = d_in[7];
  const void* nka = d_in[8];
  const void* nqb = d_in[9];
  const void* nkb = d_in[10];
  const void* aow = d_in[11];
  const void* aob = d_in[12];
  const void* bow = d_in[13];
  const void* bob = d_in[14];

  // ws carve (u16 elems), total ~176 MB:
  //   [flag][hsa' 6.29M][hsb' 1.57M][aqw' 28.3M][bqw' 28.3M][Qraw][Kraw][Vraw]
  //   Vt aliases hsa'+hsb' (exactly 7,864,320); aow'/bow' alias aqw'; Ob aliases Vraw.
  const size_t SEG = (size_t)SEQ * DMODEL;  // 7,864,320
  u16* Wp = (u16*)d_ws;
  int* flag = (int*)Wp;
  u16* hsac = Wp + 16;
  u16* hsbc = hsac + (size_t)2048 * DMODEL;
  u16* aqwc = hsbc + (size_t)SEQB * DMODEL;
  u16* bqwc = aqwc + (size_t)NQKV * DMODEL;
  u16* Qraw = bqwc + (size_t)NQKV * DMODEL;
  u16* Kraw = Qraw + SEG;
  u16* Vraw = Kraw + SEG;
  u16* Vt = hsac;                           // alias (dead after qkv gemms)
  u16* aowc = aqwc;                         // alias (converted after qkv gemms)
  u16* bowc = aqwc + (size_t)DMODEL * DMODEL;
  u16* Ob = Vraw;                           // alias (dead after build_vt)

  detect_dtype<<<1, 256, 0, stream>>>((const u16*)hsa, flag);

  const int n_hsa = 2048 * DMODEL, n_hsb = SEQB * DMODEL;
  const int n_qkvw = NQKV * DMODEL, n_ow = DMODEL * DMODEL;
  ingest<<<(n_hsa / 8 + 255) / 256, 256, 0, stream>>>(hsa, hsac, n_hsa, flag);
  ingest<<<(n_hsb / 8 + 255) / 256, 256, 0, stream>>>(hsb, hsbc, n_hsb, flag);
  ingest<<<(n_qkvw / 8 + 255) / 256, 256, 0, stream>>>(aqw, aqwc, n_qkvw, flag);
  ingest<<<(n_qkvw / 8 + 255) / 256, 256, 0, stream>>>(bqw, bqwc, n_qkvw, flag);

  // QKV projections -> ws bf16 segments (joint order: rows 0..511 = b, 512.. = a)
  gemm_bt<<<dim3(NQKV / 128, 2048 / 128), 256, 0, stream>>>(
      hsac, aqwc, aqb,
      Qraw + (size_t)SEQB * DMODEL, Kraw + (size_t)SEQB * DMODEL, Vraw + (size_t)SEQB * DMODEL,
      2048, NQKV, DMODEL, flag, 0, 0);
  gemm_bt<<<dim3(NQKV / 128, SEQB / 128), 256, 0, stream>>>(
      hsbc, bqwc, bqb, Qraw, Kraw, Vraw, SEQB, NQKV, DMODEL, flag, 0, 0);

  // out-proj weights into aliased region (aqw'/bqw' now dead)
  ingest<<<(n_ow / 8 + 255) / 256, 256, 0, stream>>>(aow, aowc, n_ow, flag);
  ingest<<<(n_ow / 8 + 255) / 256, 256, 0, stream>>>(bow, bowc, n_ow, flag);

  normrope<<<dim3(SEQ * NH * 2), 64, 0, stream>>>(Qraw, Kraw, rope, nqa, nka, nqb, nkb, flag);
  build_vt<<<dim3(NH, SEQ / 64, DHEAD / 64), 256, 0, stream>>>(Vraw, Vt);
  attn<<<dim3(SEQ / 64, NH), 256, 0, stream>>>(Qraw, Kraw, Vt, Ob);

  // output projections -> d_out (dtype per flag), row offsets 0 (out_a) / 2048 (out_b)
  gemm_bt<<<dim3(DMODEL / 128, 2048 / 128), 256, 0, stream>>>(
      Ob + (size_t)SEQB * DMODEL, aowc, aob, d_out, d_out, d_out,
      2048, DMODEL, DMODEL, flag, 1, 0);
  gemm_bt<<<dim3(DMODEL / 128, SEQB / 128), 256, 0, stream>>>(
      Ob, bowc, bob, d_out, d_out, d_out, SEQB, DMODEL, DMODEL, flag, 1, 2048);
}

// Round 4
// 1269.274 us; speedup vs baseline: 1.1743x; 1.0975x over previous
//
#include <hip/hip_runtime.h>
#include <cstdint>
#include <math.h>

typedef unsigned short u16;
typedef __bf16 bf16x8 __attribute__((ext_vector_type(8)));
typedef float f32x4 __attribute__((ext_vector_type(4)));
typedef unsigned int u32x4 __attribute__((ext_vector_type(4)));

#define NH 24
#define DHEAD 128
#define SEQ 2560
#define SEQB 512
#define DMODEL 3072
#define NQKV 9216
// fold attn scale and log2(e) into Q so softmax can use exp2 (v_exp_f32)
#define QSCALE (0.08838834764831845f * 1.4426950408889634f)

__device__ __forceinline__ float bf2f(u16 b) {
  unsigned u = ((unsigned)b) << 16;
  return __builtin_bit_cast(float, u);
}
__device__ __forceinline__ u16 f2bf(float f) {
  unsigned u = __builtin_bit_cast(unsigned, f);
  u += 0x7fffu + ((u >> 16) & 1u);
  return (u16)(u >> 16);
}
__device__ __forceinline__ unsigned pack2(float a, float b) {
  return (unsigned)f2bf(a) | ((unsigned)f2bf(b) << 16);
}

// ---------------- dtype detector: fp32 buffers read as u16 contain mantissa
// fragments whose bf16-exponent field is 0xFF with p~1/256; bf16 N(0,1) data never does.
__global__ __launch_bounds__(256) void detect_dtype(const u16* __restrict__ x, int* __restrict__ flag) {
  __shared__ int cnt;
  if (threadIdx.x == 0) cnt = 0;
  __syncthreads();
  int local = 0;
  for (int i = threadIdx.x; i < 262144; i += 256) {
    if ((x[i] & 0x7F80u) == 0x7F80u) local++;
  }
  atomicAdd(&cnt, local);
  __syncthreads();
  if (threadIdx.x == 0) *flag = (cnt > 0) ? 1 : 0;
}

// ---------------- ingest: convert fp32 -> bf16 (flag=1) or copy bf16 (flag=0)
__global__ __launch_bounds__(256) void ingest(const void* __restrict__ src, u16* __restrict__ dst,
                                              int n, const int* __restrict__ flag) {
  const bool f32 = (*flag) != 0;
  int idx = (blockIdx.x * 256 + threadIdx.x) * 8;
  if (idx + 8 <= n) {
    if (f32) {
      const float* s = (const float*)src;
      float4 v0 = *(const float4*)(s + idx);
      float4 v1 = *(const float4*)(s + idx + 4);
      u16 t[8] = {f2bf(v0.x), f2bf(v0.y), f2bf(v0.z), f2bf(v0.w),
                  f2bf(v1.x), f2bf(v1.y), f2bf(v1.z), f2bf(v1.w)};
      *(u32x4*)(dst + idx) = *(u32x4*)t;
    } else {
      *(u32x4*)(dst + idx) = *(const u32x4*)((const u16*)src + idx);
    }
  } else if (idx < n) {
    for (int j = idx; j < n; ++j)
      dst[j] = f32 ? f2bf(((const float*)src)[j]) : ((const u16*)src)[j];
  }
}

// ---------------- GEMM: out[M][N] = X[M][K] * W[N][K]^T + bias, bf16 in ws, fp32 acc
// 128x128 tile, BK=32, 4 waves x 4x4 MFMA subtiles. bias is EXTERNAL (dtype per flag).
// Output: ws bf16 segments (ext_out=0) or d_out (ext_out=1, dtype per flag), with orow0 row offset.
__global__ __launch_bounds__(256) void gemm_bt(
    const u16* __restrict__ X, const u16* __restrict__ Wt, const void* __restrict__ bias,
    void* __restrict__ out0, void* __restrict__ out1, void* __restrict__ out2,
    int M, int N, int K, const int* __restrict__ flag, int ext_out, int orow0) {
  __shared__ __align__(16) u16 Asub[128 * 32];
  __shared__ __align__(16) u16 Bsub[128 * 32];
  const int tid = threadIdx.x;
  const int wv = tid >> 6, lane = tid & 63;
  const int lhi = lane >> 4, llo = lane & 15;
  const int n0 = blockIdx.x * 128, m0 = blockIdx.y * 128;
  const int wrow = wv >> 1, wcol = wv & 1;
  f32x4 acc[4][4] = {};
  for (int k0 = 0; k0 < K; k0 += 32) {
    u32x4 areg[2], breg[2];
#pragma unroll
    for (int is = 0; is < 2; ++is) {
      int chunk = is * 256 + tid;  // 0..511
      int row = chunk >> 2, kc = (chunk & 3) << 3;
      areg[is] = *(const u32x4*)(X + (size_t)(m0 + row) * K + k0 + kc);
      breg[is] = *(const u32x4*)(Wt + (size_t)(n0 + row) * K + k0 + kc);
    }
    __syncthreads();
#pragma unroll
    for (int is = 0; is < 2; ++is) {
      int chunk = is * 256 + tid;
      *(u32x4*)&Asub[chunk * 8] = areg[is];
      *(u32x4*)&Bsub[chunk * 8] = breg[is];
    }
    __syncthreads();
    bf16x8 af[4], bfr[4];
#pragma unroll
    for (int t = 0; t < 4; ++t) {
      af[t] = *(const bf16x8*)&Asub[(wrow * 64 + t * 16 + llo) * 32 + lhi * 8];
      bfr[t] = *(const bf16x8*)&Bsub[(wcol * 64 + t * 16 + llo) * 32 + lhi * 8];
    }
#pragma unroll
    for (int i = 0; i < 4; ++i)
#pragma unroll
      for (int j = 0; j < 4; ++j)
        acc[i][j] = __builtin_amdgcn_mfma_f32_16x16x32_bf16(af[i], bfr[j], acc[i][j], 0, 0, 0);
  }
  const bool f32 = (*flag) != 0;
  const int seg = n0 / DMODEL;
  void* ob = seg == 0 ? out0 : (seg == 1 ? out1 : out2);
  const int ocol0 = n0 - seg * DMODEL;
  // epilogue: C/D layout row=(lane>>4)*4+r, col=lane&15
#pragma unroll
  for (int i = 0; i < 4; ++i) {
    int row = m0 + wrow * 64 + i * 16 + lhi * 4;
#pragma unroll
    for (int j = 0; j < 4; ++j) {
      int colin = wcol * 64 + j * 16 + llo;
      float b = f32 ? ((const float*)bias)[n0 + colin] : bf2f(((const u16*)bias)[n0 + colin]);
#pragma unroll
      for (int r = 0; r < 4; ++r) {
        float v = acc[i][j][r] + b;
        size_t off = (size_t)(orow0 + row + r) * DMODEL + ocol0 + colin;
        if (ext_out && f32) ((float*)ob)[off] = v;
        else ((u16*)ob)[off] = f2bf(v);
      }
    }
  }
}

// ---------------- RMS-norm + RoPE for Q,K, IN PLACE on Qraw/Kraw [s][3072] (bf16 ws)
// rope + norm weights are EXTERNAL (dtype per flag). 1 wave; lane holds d=2j,2j+1.
__global__ __launch_bounds__(64) void normrope(
    u16* __restrict__ Qraw, u16* __restrict__ Kraw, const void* __restrict__ rope,
    const void* __restrict__ nqa, const void* __restrict__ nka,
    const void* __restrict__ nqb, const void* __restrict__ nkb,
    const int* __restrict__ flag) {
  const bool f32 = (*flag) != 0;
  int bid = blockIdx.x;
  int which = bid & 1;  // 0=q 1=k
  int h = (bid >> 1) % NH;
  int s = bid / (NH * 2);
  int lane = threadIdx.x;
  u16* ptr = (which ? Kraw : Qraw) + (size_t)s * DMODEL + h * DHEAD + lane * 2;
  unsigned xv = *(const unsigned*)ptr;
  float x0 = bf2f((u16)(xv & 0xffff)), x1 = bf2f((u16)(xv >> 16));
  float ss = x0 * x0 + x1 * x1;
#pragma unroll
  for (int m = 1; m < 64; m <<= 1) ss += __shfl_xor(ss, m, 64);
  float rn = rsqrtf(ss * (1.0f / 128.0f) + 1e-6f);
  const void* wn = which ? (s < SEQB ? nkb : nka) : (s < SEQB ? nqb : nqa);
  float w0, w1;
  if (f32) {
    w0 = ((const float*)wn)[lane * 2];
    w1 = ((const float*)wn)[lane * 2 + 1];
  } else {
    unsigned wv2 = *(const unsigned*)((const u16*)wn + lane * 2);
    w0 = bf2f((u16)(wv2 & 0xffff));
    w1 = bf2f((u16)(wv2 >> 16));
  }
  float y0 = x0 * rn * w0;
  float y1 = x1 * rn * w1;
  // rope table: [s][64][2][2] = [[cos,-sin],[sin,cos]] -> elem0=cos, elem2=sin
  float c, sn;
  if (f32) {
    const float* rp = (const float*)rope + ((size_t)s * 64 + lane) * 4;
    float4 rv = *(const float4*)rp;
    c = rv.x;
    sn = rv.z;
  } else {
    const u16* rp = (const u16*)rope + ((size_t)s * 64 + lane) * 4;
    uint2 rv = *(const uint2*)rp;
    c = bf2f((u16)(rv.x & 0xffff));
    sn = bf2f((u16)(rv.y & 0xffff));
  }
  float o0 = c * y0 - sn * y1;
  float o1 = sn * y0 + c * y1;
  if (!which) { o0 *= QSCALE; o1 *= QSCALE; }
  *(unsigned*)ptr = pack2(o0, o1);
}

// ---------------- V transpose Vraw[s][3072] -> Vt (h, d=128, s=2560)  (bf16 ws only)
__global__ __launch_bounds__(256) void build_vt(const u16* __restrict__ Vraw, u16* __restrict__ Vt) {
  __shared__ u16 tile[64][66];
  int h = blockIdx.x, st = blockIdx.y, dt = blockIdx.z;
  int s0 = st * 64, d0 = dt * 64;
  int t = threadIdx.x;
  int sl = t >> 5, dp = (t & 31) << 1;
#pragma unroll
  for (int it = 0; it < 8; ++it) {
    int srow = sl + it * 8;
    unsigned v = *(const unsigned*)(Vraw + (size_t)(s0 + srow) * DMODEL + h * DHEAD + d0 + dp);
    tile[srow][dp] = (u16)(v & 0xffff);
    tile[srow][dp + 1] = (u16)(v >> 16);
  }
  __syncthreads();
  int dl = t >> 5, sp = (t & 31) << 1;
#pragma unroll
  for (int it = 0; it < 8; ++it) {
    int drow = dl + it * 8;
    unsigned v = (unsigned)tile[sp][drow] | ((unsigned)tile[sp + 1][drow] << 16);
    *(unsigned*)(Vt + ((size_t)h * DHEAD + d0 + drow) * SEQ + s0 + sp) = v;
  }
}

// ---------------- flash attention: 4 waves, 64 q-rows (16/wave), K-block 64 (bf16 ws only)
// LDS bank-even layouts (row strides == 4 mod 32 dwords):
//   Klds  [64][KSTRIDE=136]  (272 B/row)
//   Vtlds [128][VSTRIDE=72]  (144 B/row)
//   Plds  [4][16][PSTRIDE=72]
// Softmax fast path (T13 defer-max): if every lane's local scores are <= m+8, skip the
// cross-lane max reduce + alpha rescale entirely.  l_ kept as per-lane partial sum,
// reduced ONCE at the end.  Staging regs prefetched one tile ahead (latency hiding).
#define KVB 64
#define KSTRIDE 136
#define VSTRIDE 72
#define PSTRIDE 72
__global__ __launch_bounds__(256) void attn(
    const u16* __restrict__ Q, const u16* __restrict__ Kd, const u16* __restrict__ Vt,
    u16* __restrict__ O) {
  __shared__ __align__(16) u16 Klds[KVB * KSTRIDE];
  __shared__ __align__(16) u16 Vtlds[DHEAD * VSTRIDE];
  __shared__ __align__(16) u16 Plds[4][16 * PSTRIDE];
  const int q0 = blockIdx.x * 64;
  const int h = blockIdx.y;
  const int tid = threadIdx.x, wv = tid >> 6, lane = tid & 63;
  const int lhi = lane >> 4, llo = lane & 15;
  bf16x8 qf[4];
  const u16* qbase = Q + (size_t)(q0 + wv * 16 + llo) * DMODEL + h * DHEAD + lhi * 8;
#pragma unroll
  for (int f = 0; f < 4; ++f) qf[f] = *(const bf16x8*)(qbase + f * 32);
  float m_[4], lp[4];
  f32x4 oacc[8] = {};
#pragma unroll
  for (int r = 0; r < 4; ++r) { m_[r] = -1e30f; lp[r] = 0.f; }

  // staging registers (prefetch one K/V tile ahead)
  u32x4 kvv[4], vvv[4];
  {
#pragma unroll
    for (int is = 0; is < 4; ++is) {
      int c = is * 256 + tid;  // 0..1023
      kvv[is] = *(const u32x4*)(Kd + (size_t)(c >> 4) * DMODEL + h * DHEAD + ((c & 15) << 3));
      vvv[is] = *(const u32x4*)(Vt + ((size_t)h * DHEAD + (c >> 3)) * SEQ + ((c & 7) << 3));
    }
  }

  for (int kb = 0; kb < SEQ; kb += KVB) {
    __syncthreads();
#pragma unroll
    for (int is = 0; is < 4; ++is) {
      int c = is * 256 + tid;
      *(u32x4*)&Klds[(c >> 4) * KSTRIDE + ((c & 15) << 3)] = kvv[is];
      *(u32x4*)&Vtlds[(c >> 3) * VSTRIDE + ((c & 7) << 3)] = vvv[is];
    }
    __syncthreads();
    if (kb + KVB < SEQ) {
      int kb2 = kb + KVB;
#pragma unroll
      for (int is = 0; is < 4; ++is) {
        int c = is * 256 + tid;
        kvv[is] = *(const u32x4*)(Kd + (size_t)(kb2 + (c >> 4)) * DMODEL + h * DHEAD + ((c & 15) << 3));
        vvv[is] = *(const u32x4*)(Vt + ((size_t)h * DHEAD + (c >> 3)) * SEQ + kb2 + ((c & 7) << 3));
      }
    }
    // ---- QK^T: 4 column-tiles of 16 keys
    f32x4 sc[4];
#pragma unroll
    for (int ct = 0; ct < 4; ++ct) {
      f32x4 a = {};
#pragma unroll
      for (int f = 0; f < 4; ++f) {
        bf16x8 kf = *(const bf16x8*)&Klds[(ct * 16 + llo) * KSTRIDE + f * 32 + lhi * 8];
        a = __builtin_amdgcn_mfma_f32_16x16x32_bf16(qf[f], kf, a, 0, 0, 0);
      }
      sc[ct] = a;
    }
    // ---- softmax with defer-max fast path
    float lmax[4];
#pragma unroll
    for (int r = 0; r < 4; ++r)
      lmax[r] = fmaxf(fmaxf(sc[0][r], sc[1][r]), fmaxf(sc[2][r], sc[3][r]));
    int ok = (lmax[0] <= m_[0] + 8.f) & (lmax[1] <= m_[1] + 8.f) &
             (lmax[2] <= m_[2] + 8.f) & (lmax[3] <= m_[3] + 8.f);
    if (!__all(ok)) {
      // slow path: full cross-lane max reduce + rescale of oacc and lp
#pragma unroll
      for (int r = 0; r < 4; ++r) {
        float mx = lmax[r];
#pragma unroll
        for (int t = 1; t < 16; t <<= 1) mx = fmaxf(mx, __shfl_xor(mx, t, 64));
        float mnew = fmaxf(m_[r], mx);
        float alpha = exp2f(m_[r] - mnew);
        m_[r] = mnew;
        lp[r] *= alpha;
#pragma unroll
        for (int dt = 0; dt < 8; ++dt) oacc[dt][r] *= alpha;
      }
    }
    float p[4][4];
#pragma unroll
    for (int ct = 0; ct < 4; ++ct)
#pragma unroll
      for (int r = 0; r < 4; ++r) p[ct][r] = exp2f(sc[ct][r] - m_[r]);
#pragma unroll
    for (int r = 0; r < 4; ++r)
      lp[r] += (p[0][r] + p[1][r]) + (p[2][r] + p[3][r]);
    // ---- write P (per-wave buffer; same-wave lgkm ordering, no barrier)
    u16* pw = &Plds[wv][0];
#pragma unroll
    for (int ct = 0; ct < 4; ++ct)
#pragma unroll
      for (int r = 0; r < 4; ++r) pw[(lhi * 4 + r) * PSTRIDE + ct * 16 + llo] = f2bf(p[ct][r]);
    bf16x8 pf0 = *(const bf16x8*)&Plds[wv][llo * PSTRIDE + lhi * 8];
    bf16x8 pf1 = *(const bf16x8*)&Plds[wv][llo * PSTRIDE + 32 + lhi * 8];
    // ---- PV
#pragma unroll
    for (int dt = 0; dt < 8; ++dt) {
      bf16x8 vf0 = *(const bf16x8*)&Vtlds[(dt * 16 + llo) * VSTRIDE + lhi * 8];
      oacc[dt] = __builtin_amdgcn_mfma_f32_16x16x32_bf16(pf0, vf0, oacc[dt], 0, 0, 0);
      bf16x8 vf1 = *(const bf16x8*)&Vtlds[(dt * 16 + llo) * VSTRIDE + 32 + lhi * 8];
      oacc[dt] = __builtin_amdgcn_mfma_f32_16x16x32_bf16(pf1, vf1, oacc[dt], 0, 0, 0);
    }
  }
  // final cross-lane sum reduce of lp (once)
  float inv[4];
#pragma unroll
  for (int r = 0; r < 4; ++r) {
    float s = lp[r];
#pragma unroll
    for (int t = 1; t < 16; t <<= 1) s += __shfl_xor(s, t, 64);
    inv[r] = 1.0f / s;
  }
#pragma unroll
  for (int dt = 0; dt < 8; ++dt)
#pragma unroll
    for (int r = 0; r < 4; ++r) {
      int row = q0 + wv * 16 + lhi * 4 + r;
      int col = h * DHEAD + dt * 16 + llo;
      O[(size_t)row * DMODEL + col] = f2bf(oacc[dt][r] * inv[r]);
    }
}

extern "C" void kernel_launch(void* const* d_in, const int* in_sizes, int n_in,
                              void* d_out, int out_size, void* d_ws, size_t ws_size,
                              hipStream_t stream) {
  const void* hsa = d_in[0];
  const void* hsb = d_in[1];
  const void* rope = d_in[2];
  const void* aqw = d_in[3];
  const void* aqb = d_in[4];
  const void* bqw = d_in[5];
  const void* bqb = d_in[6];
  const void* nqa = d_in[7];
  const void* nka = d_in[8];
  const void* nqb = d_in[9];
  const void* nkb = d_in[10];
  const void* aow = d_in[11];
  const void* aob = d_in[12];
  const void* bow = d_in[13];
  const void* bob = d_in[14];

  // ws carve (u16 elems), total ~176 MB:
  //   [flag][hsa' 6.29M][hsb' 1.57M][aqw' 28.3M][bqw' 28.3M][Qraw][Kraw][Vraw]
  //   Vt aliases hsa'+hsb' (exactly 7,864,320); aow'/bow' alias aqw'; Ob aliases Vraw.
  const size_t SEG = (size_t)SEQ * DMODEL;  // 7,864,320
  u16* Wp = (u16*)d_ws;
  int* flag = (int*)Wp;
  u16* hsac = Wp + 16;
  u16* hsbc = hsac + (size_t)2048 * DMODEL;
  u16* aqwc = hsbc + (size_t)SEQB * DMODEL;
  u16* bqwc = aqwc + (size_t)NQKV * DMODEL;
  u16* Qraw = bqwc + (size_t)NQKV * DMODEL;
  u16* Kraw = Qraw + SEG;
  u16* Vraw = Kraw + SEG;
  u16* Vt = hsac;                           // alias (dead after qkv gemms)
  u16* aowc = aqwc;                         // alias (converted after qkv gemms)
  u16* bowc = aqwc + (size_t)DMODEL * DMODEL;
  u16* Ob = Vraw;                           // alias (dead after build_vt)

  detect_dtype<<<1, 256, 0, stream>>>((const u16*)hsa, flag);

  const int n_hsa = 2048 * DMODEL, n_hsb = SEQB * DMODEL;
  const int n_qkvw = NQKV * DMODEL, n_ow = DMODEL * DMODEL;
  ingest<<<(n_hsa / 8 + 255) / 256, 256, 0, stream>>>(hsa, hsac, n_hsa, flag);
  ingest<<<(n_hsb / 8 + 255) / 256, 256, 0, stream>>>(hsb, hsbc, n_hsb, flag);
  ingest<<<(n_qkvw / 8 + 255) / 256, 256, 0, stream>>>(aqw, aqwc, n_qkvw, flag);
  ingest<<<(n_qkvw / 8 + 255) / 256, 256, 0, stream>>>(bqw, bqwc, n_qkvw, flag);

  // QKV projections -> ws bf16 segments (joint order: rows 0..511 = b, 512.. = a)
  gemm_bt<<<dim3(NQKV / 128, 2048 / 128), 256, 0, stream>>>(
      hsac, aqwc, aqb,
      Qraw + (size_t)SEQB * DMODEL, Kraw + (size_t)SEQB * DMODEL, Vraw + (size_t)SEQB * DMODEL,
      2048, NQKV, DMODEL, flag, 0, 0);
  gemm_bt<<<dim3(NQKV / 128, SEQB / 128), 256, 0, stream>>>(
      hsbc, bqwc, bqb, Qraw, Kraw, Vraw, SEQB, NQKV, DMODEL, flag, 0, 0);

  // out-proj weights into aliased region (aqw'/bqw' now dead)
  ingest<<<(n_ow / 8 + 255) / 256, 256, 0, stream>>>(aow, aowc, n_ow, flag);
  ingest<<<(n_ow / 8 + 255) / 256, 256, 0, stream>>>(bow, bowc, n_ow, flag);

  normrope<<<dim3(SEQ * NH * 2), 64, 0, stream>>>(Qraw, Kraw, rope, nqa, nka, nqb, nkb, flag);
  build_vt<<<dim3(NH, SEQ / 64, DHEAD / 64), 256, 0, stream>>>(Vraw, Vt);
  attn<<<dim3(SEQ / 64, NH), 256, 0, stream>>>(Qraw, Kraw, Vt, Ob);

  // output projections -> d_out (dtype per flag), row offsets 0 (out_a) / 2048 (out_b)
  gemm_bt<<<dim3(DMODEL / 128, 2048 / 128), 256, 0, stream>>>(
      Ob + (size_t)SEQB * DMODEL, aowc, aob, d_out, d_out, d_out,
      2048, DMODEL, DMODEL, flag, 1, 0);
  gemm_bt<<<dim3(DMODEL / 128, SEQB / 128), 256, 0, stream>>>(
      Ob, bowc, bob, d_out, d_out, d_out, SEQB, DMODEL, DMODEL, flag, 1, 2048);
}